// Round 7
// baseline (458.000 us; speedup 1.0000x reference)
//
#include <hip/hip_runtime.h>
#include <math.h>

#define NEG_SLOPE 0.2f

typedef __attribute__((ext_vector_type(8))) short bf16x8;
typedef __attribute__((ext_vector_type(4))) float f32x4;
typedef __attribute__((ext_vector_type(8))) unsigned short ushort8;
typedef __attribute__((ext_vector_type(4))) unsigned short ushort4v;

__device__ __forceinline__ float b2f(unsigned short u){
  return __uint_as_float(((unsigned)u) << 16);
}
__device__ __forceinline__ unsigned short f2b(float f){
  unsigned u = __float_as_uint(f);
  return (unsigned short)((u + 0x7FFFu + ((u >> 16) & 1u)) >> 16);
}

// ---------------- init: cnt=1 (self loop) ----------------
extern "C" __global__ void k_init(int N, int* cnt){
  int n = blockIdx.x*blockDim.x + threadIdx.x;
  if(n < N) cnt[n] = 1;
}

// ---------------- CSR build ----------------
extern "C" __global__ void k_count(const int* __restrict__ dsts, int E, int* cnt){
  int e = blockIdx.x*blockDim.x + threadIdx.x;
  if(e >= E) return;
  atomicAdd(&cnt[dsts[e]], 1);
}

extern "C" __global__ void k_scan_partial(const int* __restrict__ cnt, int* part, int N){
  __shared__ int sh[256];
  int t = threadIdx.x, i = blockIdx.x*256 + t;
  sh[t] = (i < N) ? cnt[i] : 0;
  __syncthreads();
  for(int s=128; s>0; s>>=1){
    if(t < s) sh[t] += sh[t+s];
    __syncthreads();
  }
  if(t == 0) part[blockIdx.x] = sh[0];
}

extern "C" __global__ void k_scan_ex(int* part, int NB){
  __shared__ int sh[256];
  int t = threadIdx.x;
  int v = (t < NB) ? part[t] : 0;
  sh[t] = v; __syncthreads();
  for(int s=1; s<256; s<<=1){
    int u = (t >= s) ? sh[t-s] : 0;
    __syncthreads();
    sh[t] += u;
    __syncthreads();
  }
  if(t < NB) part[t] = sh[t] - v;  // exclusive
}

// also writes the scatter cursor (merged k_cursor)
extern "C" __global__ void k_scan_final(const int* __restrict__ cnt, const int* __restrict__ part,
                                        int* offs, int* cur, int N){
  __shared__ int sh[256];
  int t = threadIdx.x, i = blockIdx.x*256 + t;
  int v = (i < N) ? cnt[i] : 0;
  sh[t] = v; __syncthreads();
  for(int s=1; s<256; s<<=1){
    int u = (t >= s) ? sh[t-s] : 0;
    __syncthreads();
    sh[t] += u;
    __syncthreads();
  }
  int ex = part[blockIdx.x] + sh[t] - v;
  if(i < N){ offs[i] = ex; cur[i] = ex; }
  if(i == N-1) offs[N] = ex + v;
}

extern "C" __global__ void k_scatter(const int* __restrict__ srcs, const int* __restrict__ dsts,
                                     int E, int N, int* cur, int* csr){
  int i = blockIdx.x*blockDim.x + threadIdx.x;
  if(i >= E + N) return;
  int s, d;
  if(i < E){ s = srcs[i]; d = dsts[i]; } else { s = d = i - E; }
  int pos = atomicAdd(&cur[d], 1);
  csr[pos] = s;
}

// ---- sort each node's adjacency segment by src id (L2 locality in gathers) ----
// one wave per node; odd-even transposition over 64 slots via shfl. deg>64: skip (rare).
extern "C" __global__ void k_sortadj(const int* __restrict__ offs, int* __restrict__ csr, int N){
  int n = blockIdx.x*4 + (threadIdx.x >> 6);
  if(n >= N) return;
  int lane = threadIdx.x & 63;
  int beg = offs[n], end = offs[n+1];
  int d = end - beg;
  if(d <= 1 || d > 64) return;
  int v = (lane < d) ? csr[beg + lane] : 0x7FFFFFFF;
  #pragma unroll
  for(int r=0; r<64; r++){
    int odd = r & 1;
    int p = ((lane ^ odd) & 1) ? lane - 1 : lane + 1;
    if(p < 0 || p > 63) p = lane;
    int u = __shfl(v, p);
    int mn = min(v,u), mx = max(v,u);
    v = (p == lane) ? v : ((p > lane) ? mn : mx);
  }
  if(lane < d) csr[beg + lane] = v;
}

// ---------------- fp32 -> bf16 cast (8 elems/thread) ----------------
extern "C" __global__ void k_cast_x(const float* __restrict__ x, unsigned short* __restrict__ xb, int n8){
  int i = blockIdx.x*blockDim.x + threadIdx.x;
  if(i >= n8) return;
  const float4* p = (const float4*)(x + (size_t)i*8);
  float4 v0 = p[0], v1 = p[1];
  ushort8 o;
  o[0]=f2b(v0.x); o[1]=f2b(v0.y); o[2]=f2b(v0.z); o[3]=f2b(v0.w);
  o[4]=f2b(v1.x); o[5]=f2b(v1.y); o[6]=f2b(v1.z); o[7]=f2b(v1.w);
  *(ushort8*)(xb + (size_t)i*8) = o;
}

// ---------------- weight transpose+concat (both layers, one launch) ----------------
extern "C" __global__ void k_wt2(const float* __restrict__ W0, const float* __restrict__ Wr0,
                                 const float* __restrict__ W1, const float* __restrict__ Wr1,
                                 unsigned short* __restrict__ WT0, unsigned short* __restrict__ WT1){
  int idx = blockIdx.x*256 + threadIdx.x;
  const int tot0 = 512*256;
  if(idx < tot0){
    int n = idx >> 8, k = idx & 255;
    const float* W = (n < 256) ? W0 : Wr0;
    int c = (n < 256) ? n : n - 256;
    WT0[idx] = f2b(W[(size_t)k*256 + c]);
  } else {
    idx -= tot0;
    if(idx >= 128*256) return;
    int n = idx >> 8, k = idx & 255;
    const float* W = (n < 64) ? W1 : Wr1;
    int c = (n < 64) ? n : n - 64;
    WT1[idx] = f2b(W[(size_t)k*64 + c]);
  }
}

// ---------------- bf16 MFMA GEMM: C[M][NC] = A[M][256] @ WT[NC][256]^T ----------------
__launch_bounds__(256)
extern "C" __global__ void k_mgemm(const unsigned short* __restrict__ A,
                                   const unsigned short* __restrict__ WT,
                                   unsigned short* __restrict__ C, int ldc, int M){
  __shared__ unsigned short As[128*64];
  __shared__ unsigned short Bs[128*64];
  int t = threadIdx.x;
  int lane = t & 63, wid = t >> 6;
  int wr = wid >> 1, wc = wid & 1;
  int row0 = blockIdx.y*128, col0 = blockIdx.x*128;
  f32x4 acc[4][4] = {};

  for(int k0 = 0; k0 < 256; k0 += 64){
    #pragma unroll
    for(int i=0; i<4; i++){
      int t2 = i*256 + t;
      int r = t2 >> 3;
      int dslot = (t2 & 7) ^ (r & 7);
      int gr = row0 + r; if(gr >= M) gr = M - 1;
      const unsigned short* ga = A + (size_t)gr*256 + k0 + dslot*8;
      __builtin_amdgcn_global_load_lds((const __attribute__((address_space(1))) unsigned*)ga,
          (__attribute__((address_space(3))) unsigned*)(As + i*2048 + wid*512), 16, 0, 0);
      const unsigned short* gb = WT + (size_t)(col0 + r)*256 + k0 + dslot*8;
      __builtin_amdgcn_global_load_lds((const __attribute__((address_space(1))) unsigned*)gb,
          (__attribute__((address_space(3))) unsigned*)(Bs + i*2048 + wid*512), 16, 0, 0);
    }
    __syncthreads();
    #pragma unroll
    for(int kc=0; kc<2; kc++){
      bf16x8 a[4], b[4];
      int kb = kc*4 + (lane >> 4);
      #pragma unroll
      for(int f=0; f<4; f++){
        int ar = wr*64 + f*16 + (lane & 15);
        a[f] = *(const bf16x8*)&As[ar*64 + ((kb ^ (ar & 7))*8)];
        int br = wc*64 + f*16 + (lane & 15);
        b[f] = *(const bf16x8*)&Bs[br*64 + ((kb ^ (br & 7))*8)];
      }
      #pragma unroll
      for(int fm=0; fm<4; fm++)
        #pragma unroll
        for(int fn=0; fn<4; fn++)
          acc[fm][fn] = __builtin_amdgcn_mfma_f32_16x16x32_bf16(a[fm], b[fn], acc[fm][fn], 0, 0, 0);
    }
    __syncthreads();
  }

  int rb = row0 + wr*64 + ((lane >> 4) << 2);
  int cb = col0 + wc*64 + (lane & 15);
  #pragma unroll
  for(int fm=0; fm<4; fm++){
    #pragma unroll
    for(int r=0; r<4; r++){
      int row = rb + fm*16 + r;
      if(row < M){
        #pragma unroll
        for(int fn=0; fn<4; fn++)
          C[(size_t)row*ldc + cb + fn*16] = f2b(acc[fm][fn][r]);
      }
    }
  }
}

// ---------------- attention logits layer0 (bf16 h0) ----------------
extern "C" __global__ void k_al0(const unsigned short* __restrict__ buf0b, const float* __restrict__ as0,
                                 const float* __restrict__ ad0, float* als0, float* ald0, int N){
  int i = blockIdx.x*blockDim.x + threadIdx.x;   // n*8+h
  if(i >= N*8) return;
  int n = i >> 3, h = i & 7;
  const uint4* hp = (const uint4*)(buf0b + (size_t)n*512 + h*32);
  const float* av = as0 + h*32;
  const float* dv = ad0 + h*32;
  float s = 0.f, d = 0.f;
  #pragma unroll
  for(int q=0; q<4; q++){
    uint4 u = hp[q];
    unsigned w[4] = {u.x, u.y, u.z, u.w};
    #pragma unroll
    for(int j=0; j<4; j++){
      float lo = __uint_as_float(w[j] << 16);
      float hi = __uint_as_float(w[j] & 0xFFFF0000u);
      int c = q*8 + j*2;
      s += lo*av[c] + hi*av[c+1];
      d += lo*dv[c] + hi*dv[c+1];
    }
  }
  als0[i] = s; ald0[i] = d;
}

// ---- alpha layer0: unnormalized p=exp(leakyrelu(logit)) bf16 in CSR order + rden0[n*8+h] ----
// wave per node; lane = (slot j = lane>>3, head h = lane&7). No max subtraction:
// logits are O(+-10) (unit-variance tensors), exp fp32-safe, softmax shift-invariant.
extern "C" __global__ void k_palpha0(const float* __restrict__ als0, const float* __restrict__ ald0,
                                     const int* __restrict__ offs, const int* __restrict__ csr,
                                     unsigned short* __restrict__ alpha0b, float* __restrict__ rden0, int N){
  int n = blockIdx.x*4 + (threadIdx.x >> 6);
  if(n >= N) return;
  int lane = threadIdx.x & 63;
  int j = lane >> 3, h = lane & 7;
  float ald_n = ald0[n*8+h];
  int beg = offs[n], end = offs[n+1];
  float den = 0.f;
  for(int k = beg + j; k < end; k += 8){
    int s = csr[k];
    float v = als0[s*8+h] + ald_n;
    v = v > 0.f ? v : NEG_SLOPE*v;
    float p = expf(v);
    den += p;
    alpha0b[(size_t)k*8 + h] = f2b(p);
  }
  #pragma unroll
  for(int o=8; o<64; o<<=1) den += __shfl_xor(den, o);   // reduce over j, keep h
  if(j == 0) rden0[n*8+h] = 1.f/(den + 1e-16f);
}

// ---- gather layer0: sum of p*feature, normalize once; block-per-node, 4-way split ----
// lane owns channels c=lane*4..lane*4+3, all in head lane>>3.
__launch_bounds__(256)
extern "C" __global__ void k_gather0(const unsigned short* __restrict__ buf0b,
                                     const unsigned short* __restrict__ alpha0b,
                                     const float* __restrict__ rden0,
                                     const int* __restrict__ offs, const int* __restrict__ csr,
                                     const float* __restrict__ b0, const float* __restrict__ br0,
                                     unsigned short* __restrict__ h1b, int N){
  __shared__ float4 smv[3][64];
  int n = blockIdx.x;
  int t = threadIdx.x;
  int lane = t & 63, w = t >> 6;
  int h = lane >> 3;
  int c = lane*4;
  int beg = offs[n], end = offs[n+1];

  float a0=0.f, a1=0.f, a2=0.f, a3=0.f;

  int k = beg + w;
  unsigned short p_cur = 0; uint2 u_cur; u_cur.x = 0; u_cur.y = 0;
  if(k < end){
    int s  = csr[k];
    p_cur  = __builtin_nontemporal_load(&alpha0b[(size_t)k*8 + h]);
    u_cur  = *(const uint2*)(buf0b + (size_t)s*512 + c);
  }
  while(k < end){
    int k2 = k + 4;
    unsigned short p_nx = 0; uint2 u_nx; u_nx.x = 0; u_nx.y = 0;
    if(k2 < end){
      int s  = csr[k2];
      p_nx   = __builtin_nontemporal_load(&alpha0b[(size_t)k2*8 + h]);
      u_nx   = *(const uint2*)(buf0b + (size_t)s*512 + c);
    }
    float p = b2f(p_cur);
    a0 = fmaf(p, __uint_as_float(u_cur.x << 16),         a0);
    a1 = fmaf(p, __uint_as_float(u_cur.x & 0xFFFF0000u), a1);
    a2 = fmaf(p, __uint_as_float(u_cur.y << 16),         a2);
    a3 = fmaf(p, __uint_as_float(u_cur.y & 0xFFFF0000u), a3);
    p_cur = p_nx; u_cur = u_nx;
    k = k2;
  }

  if(w != 0){
    float4 v; v.x=a0; v.y=a1; v.z=a2; v.w=a3;
    smv[w-1][lane] = v;
  }
  __syncthreads();
  if(w != 0) return;
  #pragma unroll
  for(int jj=0; jj<3; jj++){
    float4 v = smv[jj][lane];
    a0 += v.x; a1 += v.y; a2 += v.z; a3 += v.w;
  }
  float rden = rden0[n*8 + h];
  a0 *= rden; a1 *= rden; a2 *= rden; a3 *= rden;

  float4 bb = *(const float4*)(b0 + c);
  float4 rb = *(const float4*)(br0 + c);
  uint2 ru = *(const uint2*)(buf0b + (size_t)n*512 + 256 + c);
  float o0 = a0 + bb.x + __uint_as_float(ru.x << 16)         + rb.x;
  float o1 = a1 + bb.y + __uint_as_float(ru.x & 0xFFFF0000u) + rb.y;
  float o2 = a2 + bb.z + __uint_as_float(ru.y << 16)         + rb.z;
  float o3 = a3 + bb.w + __uint_as_float(ru.y & 0xFFFF0000u) + rb.w;
  ushort4v o;
  o[0] = f2b(o0 > 0.f ? o0 : expf(o0) - 1.f);
  o[1] = f2b(o1 > 0.f ? o1 : expf(o1) - 1.f);
  o[2] = f2b(o2 > 0.f ? o2 : expf(o2) - 1.f);
  o[3] = f2b(o3 > 0.f ? o3 : expf(o3) - 1.f);
  *(ushort4v*)(h1b + (size_t)n*256 + c) = o;
}

// ---------------- layer1 logits (bf16 g1) ----------------
extern "C" __global__ void k_al1(const unsigned short* __restrict__ buf1b, const float* __restrict__ as1,
                                 const float* __restrict__ ad1, float* als1, float* ald1, int N){
  int n = blockIdx.x*4 + (threadIdx.x >> 6);
  if(n >= N) return;
  int lane = threadIdx.x & 63;
  float g = b2f(buf1b[(size_t)n*128 + lane]);
  float s = g*as1[lane], d = g*ad1[lane];
  #pragma unroll
  for(int o=32; o>0; o>>=1){ s += __shfl_xor(s,o); d += __shfl_xor(d,o); }
  if(lane == 0){ als1[n] = s; ald1[n] = d; }
}

// ---- alpha layer1: unnormalized p fp32 in CSR order + rden1[n] ----
extern "C" __global__ void k_palpha1(const float* __restrict__ als1, const float* __restrict__ ald1,
                                     const int* __restrict__ offs, const int* __restrict__ csr,
                                     float* __restrict__ alpha1, float* __restrict__ rden1, int N){
  int n = blockIdx.x*4 + (threadIdx.x >> 6);
  if(n >= N) return;
  int lane = threadIdx.x & 63;
  float ald_n = ald1[n];
  int beg = offs[n], end = offs[n+1];
  float den = 0.f;
  for(int k = beg + lane; k < end; k += 64){
    int s = csr[k];
    float v = als1[s] + ald_n;
    v = v > 0.f ? v : NEG_SLOPE*v;
    float p = expf(v);
    den += p;
    alpha1[k] = p;
  }
  #pragma unroll
  for(int o=32; o>0; o>>=1) den += __shfl_xor(den, o);
  if(lane == 0) rden1[n] = 1.f/(den + 1e-16f);
}

// ---- gather layer1: sum + normalize + bias + residual + log_softmax; block-per-node ----
__launch_bounds__(256)
extern "C" __global__ void k_gather1(const unsigned short* __restrict__ buf1b,
                                     const float* __restrict__ alpha1,
                                     const float* __restrict__ rden1,
                                     const int* __restrict__ offs, const int* __restrict__ csr,
                                     const float* __restrict__ b1, const float* __restrict__ br1,
                                     float* __restrict__ out, int N){
  __shared__ float smv[3][64];
  int n = blockIdx.x;
  int t = threadIdx.x;
  int lane = t & 63, w = t >> 6;
  int beg = offs[n], end = offs[n+1];

  float acc = 0.f;
  int k = beg + w;
  float a_cur = 0.f; unsigned short f_cur = 0;
  if(k < end){
    int s = csr[k];
    a_cur = __builtin_nontemporal_load(&alpha1[k]);
    f_cur = buf1b[(size_t)s*128 + lane];
  }
  while(k < end){
    int k2 = k + 4;
    float a_nx = 0.f; unsigned short f_nx = 0;
    if(k2 < end){
      int s = csr[k2];
      a_nx = __builtin_nontemporal_load(&alpha1[k2]);
      f_nx = buf1b[(size_t)s*128 + lane];
    }
    acc = fmaf(a_cur, b2f(f_cur), acc);
    a_cur = a_nx; f_cur = f_nx;
    k = k2;
  }

  if(w != 0) smv[w-1][lane] = acc;
  __syncthreads();
  if(w != 0) return;
  #pragma unroll
  for(int jj=0; jj<3; jj++) acc += smv[jj][lane];
  acc *= rden1[n];

  float val = acc + b1[lane] + b2f(buf1b[(size_t)n*128 + 64 + lane]) + br1[lane];
  float mx = val;
  #pragma unroll
  for(int o=32; o>0; o>>=1) mx = fmaxf(mx, __shfl_xor(mx,o));
  float ex = expf(val - mx), smn = ex;
  #pragma unroll
  for(int o=32; o>0; o>>=1) smn += __shfl_xor(smn,o);
  out[(size_t)n*64 + lane] = val - mx - logf(smn);
}

// ---------------- launch ----------------
extern "C" void kernel_launch(void* const* d_in, const int* in_sizes, int n_in,
                              void* d_out, int out_size, void* d_ws, size_t ws_size,
                              hipStream_t stream){
  const float* x   = (const float*)d_in[0];
  const int*   ei  = (const int*)  d_in[1];
  const float* W0  = (const float*)d_in[2];
  const float* as0 = (const float*)d_in[3];
  const float* ad0 = (const float*)d_in[4];
  const float* b0  = (const float*)d_in[5];
  const float* Wr0 = (const float*)d_in[6];
  const float* br0 = (const float*)d_in[7];
  const float* W1  = (const float*)d_in[8];
  const float* as1 = (const float*)d_in[9];
  const float* ad1 = (const float*)d_in[10];
  const float* b1  = (const float*)d_in[11];
  const float* Wr1 = (const float*)d_in[12];
  const float* br1 = (const float*)d_in[13];
  int N = in_sizes[0] / 256;
  int E = in_sizes[1] / 2;
  const int* srcs = ei;
  const int* dsts = ei + E;
  float* out = (float*)d_out;

  // workspace layout (bf16 feature buffers)
  unsigned short* buf0b = (unsigned short*)d_ws;        // N*512 bf16 (h0 | r0)
  unsigned short* xb    = buf0b + (size_t)N*512;        // N*256 bf16 (dead after mgemm0)
  unsigned short* h1b   = xb    + (size_t)N*256;        // N*256 bf16
  unsigned short* buf1b = h1b   + (size_t)N*256;        // N*128 bf16 (g1 | r1)
  unsigned short* WT0   = buf1b + (size_t)N*128;        // 512*256 bf16
  unsigned short* WT1   = WT0   + 512*256;              // 128*256 bf16
  float*    als0 = (float*)(WT1 + 128*256);             // N*8
  float*    ald0 = als0 + (size_t)N*8;                  // N*8
  float*    als1 = ald0 + (size_t)N*8;                  // N
  float*    ald1 = als1 + N;                            // N
  float*    rden0 = ald1 + N;                           // N*8
  float*    rden1 = rden0 + (size_t)N*8;                // N
  int*      cnt  = (int*)(rden1 + N);                   // N (also cursor)
  int*      offs = cnt + N;                             // N+1
  int*      part = offs + N + 1;                        // 256
  int*      csr  = part + 256;                          // E+N
  // alpha buffers overlay xb (xb dead once mgemm0 has consumed it)
  unsigned short* alpha0b = xb;                          // (E+N)*8 bf16
  float*          alpha1  = (float*)(xb + (size_t)(E+N)*8);  // (E+N) fp32

  int NB = (N + 255) / 256;
  int ET = E + N;

  // CSR build + per-node src-sort
  hipLaunchKernelGGL(k_init, dim3((N+255)/256), dim3(256), 0, stream, N, cnt);
  hipLaunchKernelGGL(k_count, dim3((E+255)/256), dim3(256), 0, stream, dsts, E, cnt);
  hipLaunchKernelGGL(k_scan_partial, dim3(NB), dim3(256), 0, stream, cnt, part, N);
  hipLaunchKernelGGL(k_scan_ex, dim3(1), dim3(256), 0, stream, part, NB);
  hipLaunchKernelGGL(k_scan_final, dim3(NB), dim3(256), 0, stream, cnt, part, offs, cnt, N);
  hipLaunchKernelGGL(k_scatter, dim3((ET+255)/256), dim3(256), 0, stream, srcs, dsts, E, N, cnt, csr);
  hipLaunchKernelGGL(k_sortadj, dim3((N+3)/4), dim3(256), 0, stream, offs, csr, N);

  // casts / weight prep
  int n8 = N*256/8;
  hipLaunchKernelGGL(k_cast_x, dim3((n8+255)/256), dim3(256), 0, stream, x, xb, n8);
  hipLaunchKernelGGL(k_wt2, dim3((512*256+128*256+255)/256), dim3(256), 0, stream, W0, Wr0, W1, Wr1, WT0, WT1);

  int MB = (N + 127) / 128;
  // layer0: buf0b[N][512] = xb @ [W0|Wr0]
  hipLaunchKernelGGL(k_mgemm, dim3(4, MB), dim3(256), 0, stream, xb, WT0, buf0b, 512, N);
  hipLaunchKernelGGL(k_al0, dim3((N*8+255)/256), dim3(256), 0, stream, buf0b, as0, ad0, als0, ald0, N);
  hipLaunchKernelGGL(k_palpha0, dim3((N+3)/4), dim3(256), 0, stream, als0, ald0, offs, csr, alpha0b, rden0, N);
  hipLaunchKernelGGL(k_gather0, dim3(N), dim3(256), 0, stream, buf0b, alpha0b, rden0, offs, csr, b0, br0, h1b, N);

  // layer1: buf1b[N][128] = h1b @ [W1|Wr1]
  hipLaunchKernelGGL(k_mgemm, dim3(1, MB), dim3(256), 0, stream, h1b, WT1, buf1b, 128, N);
  hipLaunchKernelGGL(k_al1, dim3((N+3)/4), dim3(256), 0, stream, buf1b, as1, ad1, als1, ald1, N);
  hipLaunchKernelGGL(k_palpha1, dim3((N+3)/4), dim3(256), 0, stream, als1, ald1, offs, csr, alpha1, rden1, N);
  hipLaunchKernelGGL(k_gather1, dim3(N), dim3(256), 0, stream, buf1b, alpha1, rden1, offs, csr, b1, br1, out, N);
}

// Round 8
// 353.648 us; speedup vs baseline: 1.2951x; 1.2951x over previous
//
#include <hip/hip_runtime.h>
#include <math.h>

#define NEG_SLOPE 0.2f

typedef __attribute__((ext_vector_type(8))) short bf16x8;
typedef __attribute__((ext_vector_type(4))) float f32x4;
typedef __attribute__((ext_vector_type(8))) unsigned short ushort8;
typedef __attribute__((ext_vector_type(4))) unsigned short ushort4v;

__device__ __forceinline__ float b2f(unsigned short u){
  return __uint_as_float(((unsigned)u) << 16);
}
__device__ __forceinline__ unsigned short f2b(float f){
  unsigned u = __float_as_uint(f);
  return (unsigned short)((u + 0x7FFFu + ((u >> 16) & 1u)) >> 16);
}

// ---------------- init: cnt=1 (self loop) ----------------
extern "C" __global__ void k_init(int N, int* cnt){
  int n = blockIdx.x*blockDim.x + threadIdx.x;
  if(n < N) cnt[n] = 1;
}

// ---------------- CSR build ----------------
extern "C" __global__ void k_count(const int* __restrict__ dsts, int E, int* cnt){
  int e = blockIdx.x*blockDim.x + threadIdx.x;
  if(e >= E) return;
  atomicAdd(&cnt[dsts[e]], 1);
}

extern "C" __global__ void k_scan_partial(const int* __restrict__ cnt, int* part, int N){
  __shared__ int sh[256];
  int t = threadIdx.x, i = blockIdx.x*256 + t;
  sh[t] = (i < N) ? cnt[i] : 0;
  __syncthreads();
  for(int s=128; s>0; s>>=1){
    if(t < s) sh[t] += sh[t+s];
    __syncthreads();
  }
  if(t == 0) part[blockIdx.x] = sh[0];
}

extern "C" __global__ void k_scan_ex(int* part, int NB){
  __shared__ int sh[256];
  int t = threadIdx.x;
  int v = (t < NB) ? part[t] : 0;
  sh[t] = v; __syncthreads();
  for(int s=1; s<256; s<<=1){
    int u = (t >= s) ? sh[t-s] : 0;
    __syncthreads();
    sh[t] += u;
    __syncthreads();
  }
  if(t < NB) part[t] = sh[t] - v;  // exclusive
}

// also writes the scatter cursor (merged k_cursor)
extern "C" __global__ void k_scan_final(const int* __restrict__ cnt, const int* __restrict__ part,
                                        int* offs, int* cur, int N){
  __shared__ int sh[256];
  int t = threadIdx.x, i = blockIdx.x*256 + t;
  int v = (i < N) ? cnt[i] : 0;
  sh[t] = v; __syncthreads();
  for(int s=1; s<256; s<<=1){
    int u = (t >= s) ? sh[t-s] : 0;
    __syncthreads();
    sh[t] += u;
    __syncthreads();
  }
  int ex = part[blockIdx.x] + sh[t] - v;
  if(i < N){ offs[i] = ex; cur[i] = ex; }
  if(i == N-1) offs[N] = ex + v;
}

extern "C" __global__ void k_scatter(const int* __restrict__ srcs, const int* __restrict__ dsts,
                                     int E, int N, int* cur, int* csr){
  int i = blockIdx.x*blockDim.x + threadIdx.x;
  if(i >= E + N) return;
  int s, d;
  if(i < E){ s = srcs[i]; d = dsts[i]; } else { s = d = i - E; }
  int pos = atomicAdd(&cur[d], 1);
  csr[pos] = s;
}

// ---------------- fp32 -> bf16 cast (8 elems/thread) ----------------
extern "C" __global__ void k_cast_x(const float* __restrict__ x, unsigned short* __restrict__ xb, int n8){
  int i = blockIdx.x*blockDim.x + threadIdx.x;
  if(i >= n8) return;
  const float4* p = (const float4*)(x + (size_t)i*8);
  float4 v0 = p[0], v1 = p[1];
  ushort8 o;
  o[0]=f2b(v0.x); o[1]=f2b(v0.y); o[2]=f2b(v0.z); o[3]=f2b(v0.w);
  o[4]=f2b(v1.x); o[5]=f2b(v1.y); o[6]=f2b(v1.z); o[7]=f2b(v1.w);
  *(ushort8*)(xb + (size_t)i*8) = o;
}

// ---------------- weight transpose+concat (both layers, one launch) ----------------
extern "C" __global__ void k_wt2(const float* __restrict__ W0, const float* __restrict__ Wr0,
                                 const float* __restrict__ W1, const float* __restrict__ Wr1,
                                 unsigned short* __restrict__ WT0, unsigned short* __restrict__ WT1){
  int idx = blockIdx.x*256 + threadIdx.x;
  const int tot0 = 512*256;
  if(idx < tot0){
    int n = idx >> 8, k = idx & 255;
    const float* W = (n < 256) ? W0 : Wr0;
    int c = (n < 256) ? n : n - 256;
    WT0[idx] = f2b(W[(size_t)k*256 + c]);
  } else {
    idx -= tot0;
    if(idx >= 128*256) return;
    int n = idx >> 8, k = idx & 255;
    const float* W = (n < 64) ? W1 : Wr1;
    int c = (n < 64) ? n : n - 64;
    WT1[idx] = f2b(W[(size_t)k*64 + c]);
  }
}

// ---------------- bf16 MFMA GEMM: C[M][NC] = A[M][256] @ WT[NC][256]^T ----------------
__launch_bounds__(256)
extern "C" __global__ void k_mgemm(const unsigned short* __restrict__ A,
                                   const unsigned short* __restrict__ WT,
                                   unsigned short* __restrict__ C, int ldc, int M){
  __shared__ unsigned short As[128*64];
  __shared__ unsigned short Bs[128*64];
  int t = threadIdx.x;
  int lane = t & 63, wid = t >> 6;
  int wr = wid >> 1, wc = wid & 1;
  int row0 = blockIdx.y*128, col0 = blockIdx.x*128;
  f32x4 acc[4][4] = {};

  for(int k0 = 0; k0 < 256; k0 += 64){
    #pragma unroll
    for(int i=0; i<4; i++){
      int t2 = i*256 + t;
      int r = t2 >> 3;
      int dslot = (t2 & 7) ^ (r & 7);
      int gr = row0 + r; if(gr >= M) gr = M - 1;
      const unsigned short* ga = A + (size_t)gr*256 + k0 + dslot*8;
      __builtin_amdgcn_global_load_lds((const __attribute__((address_space(1))) unsigned*)ga,
          (__attribute__((address_space(3))) unsigned*)(As + i*2048 + wid*512), 16, 0, 0);
      const unsigned short* gb = WT + (size_t)(col0 + r)*256 + k0 + dslot*8;
      __builtin_amdgcn_global_load_lds((const __attribute__((address_space(1))) unsigned*)gb,
          (__attribute__((address_space(3))) unsigned*)(Bs + i*2048 + wid*512), 16, 0, 0);
    }
    __syncthreads();
    #pragma unroll
    for(int kc=0; kc<2; kc++){
      bf16x8 a[4], b[4];
      int kb = kc*4 + (lane >> 4);
      #pragma unroll
      for(int f=0; f<4; f++){
        int ar = wr*64 + f*16 + (lane & 15);
        a[f] = *(const bf16x8*)&As[ar*64 + ((kb ^ (ar & 7))*8)];
        int br = wc*64 + f*16 + (lane & 15);
        b[f] = *(const bf16x8*)&Bs[br*64 + ((kb ^ (br & 7))*8)];
      }
      #pragma unroll
      for(int fm=0; fm<4; fm++)
        #pragma unroll
        for(int fn=0; fn<4; fn++)
          acc[fm][fn] = __builtin_amdgcn_mfma_f32_16x16x32_bf16(a[fm], b[fn], acc[fm][fn], 0, 0, 0);
    }
    __syncthreads();
  }

  int rb = row0 + wr*64 + ((lane >> 4) << 2);
  int cb = col0 + wc*64 + (lane & 15);
  #pragma unroll
  for(int fm=0; fm<4; fm++){
    #pragma unroll
    for(int r=0; r<4; r++){
      int row = rb + fm*16 + r;
      if(row < M){
        #pragma unroll
        for(int fn=0; fn<4; fn++)
          C[(size_t)row*ldc + cb + fn*16] = f2b(acc[fm][fn][r]);
      }
    }
  }
}

// ---------------- attention logits layer0 (bf16 h0) ----------------
extern "C" __global__ void k_al0(const unsigned short* __restrict__ buf0b, const float* __restrict__ as0,
                                 const float* __restrict__ ad0, float* als0, float* ald0, int N){
  int i = blockIdx.x*blockDim.x + threadIdx.x;   // n*8+h
  if(i >= N*8) return;
  int n = i >> 3, h = i & 7;
  const uint4* hp = (const uint4*)(buf0b + (size_t)n*512 + h*32);
  const float* av = as0 + h*32;
  const float* dv = ad0 + h*32;
  float s = 0.f, d = 0.f;
  #pragma unroll
  for(int q=0; q<4; q++){
    uint4 u = hp[q];
    unsigned w[4] = {u.x, u.y, u.z, u.w};
    #pragma unroll
    for(int j=0; j<4; j++){
      float lo = __uint_as_float(w[j] << 16);
      float hi = __uint_as_float(w[j] & 0xFFFF0000u);
      int c = q*8 + j*2;
      s += lo*av[c] + hi*av[c+1];
      d += lo*dv[c] + hi*dv[c+1];
    }
  }
  als0[i] = s; ald0[i] = d;
}

// ---- gather layer0: fused LDS-alpha (chunked) + pair-MLP weighted gather ----
// block per node; lane owns channels c=lane*4..lane*4+3, head h=lane>>3.
// No max subtraction: logits are O(+-10) (unit-variance tensors), exp fp32-safe,
// softmax shift-invariant.
#define CH 64
__launch_bounds__(256)
extern "C" __global__ void k_gather0(const unsigned short* __restrict__ buf0b,
                                     const float* __restrict__ als0, const float* __restrict__ ald0,
                                     const int* __restrict__ offs, const int* __restrict__ csr,
                                     const float* __restrict__ b0, const float* __restrict__ br0,
                                     unsigned short* __restrict__ h1b, int N){
  __shared__ float s_alpha[CH][8];
  __shared__ int   s_src[CH];
  __shared__ float s_den[8];
  __shared__ float4 smv[3][64];
  int n = blockIdx.x;
  int t = threadIdx.x;
  int lane = t & 63, w = t >> 6;
  int h = lane >> 3;
  int c = lane*4;
  int beg = offs[n], end = offs[n+1];
  int hh = t & 7;                       // head this thread computes alpha for
  float ald_n = ald0[n*8 + hh];

  if(t < 8) s_den[t] = 0.f;

  float a0=0.f, a1=0.f, a2=0.f, a3=0.f;

  for(int chunk = beg; chunk < end; chunk += CH){
    int m = end - chunk; if(m > CH) m = CH;
    __syncthreads();                    // den-init visible / prev phase B done
    // phase A: alpha for m edges x 8 heads (each computed exactly once)
    for(int idx = t; idx < m*8; idx += 256){
      int e = idx >> 3;
      int s = csr[chunk + e];
      if(hh == 0) s_src[e] = s;
      float v = als0[s*8 + hh] + ald_n;
      v = v > 0.f ? v : NEG_SLOPE*v;
      float p = expf(v);
      s_alpha[e][hh] = p;
      atomicAdd(&s_den[hh], p);
    }
    __syncthreads();
    // phase B: pair-wise gather (2 feature loads in flight per wave)
    for(int base = w; base < m; base += 8){
      int ea = base, eb = base + 4;
      bool vb = eb < m;
      int sa = s_src[ea];
      int sb = vb ? s_src[eb] : sa;
      float pa = s_alpha[ea][h];
      float pb = vb ? s_alpha[eb][h] : 0.f;
      uint2 ua = *(const uint2*)(buf0b + (size_t)sa*512 + c);
      uint2 ub = *(const uint2*)(buf0b + (size_t)sb*512 + c);
      a0 = fmaf(pa, __uint_as_float(ua.x << 16),         a0);
      a1 = fmaf(pa, __uint_as_float(ua.x & 0xFFFF0000u), a1);
      a2 = fmaf(pa, __uint_as_float(ua.y << 16),         a2);
      a3 = fmaf(pa, __uint_as_float(ua.y & 0xFFFF0000u), a3);
      a0 = fmaf(pb, __uint_as_float(ub.x << 16),         a0);
      a1 = fmaf(pb, __uint_as_float(ub.x & 0xFFFF0000u), a1);
      a2 = fmaf(pb, __uint_as_float(ub.y << 16),         a2);
      a3 = fmaf(pb, __uint_as_float(ub.y & 0xFFFF0000u), a3);
    }
  }

  if(w != 0){
    float4 v; v.x=a0; v.y=a1; v.z=a2; v.w=a3;
    smv[w-1][lane] = v;
  }
  __syncthreads();
  if(w != 0) return;
  #pragma unroll
  for(int jj=0; jj<3; jj++){
    float4 v = smv[jj][lane];
    a0 += v.x; a1 += v.y; a2 += v.z; a3 += v.w;
  }
  float rden = 1.f/(s_den[h] + 1e-16f);
  a0 *= rden; a1 *= rden; a2 *= rden; a3 *= rden;

  float4 bb = *(const float4*)(b0 + c);
  float4 rb = *(const float4*)(br0 + c);
  uint2 ru = *(const uint2*)(buf0b + (size_t)n*512 + 256 + c);
  float o0 = a0 + bb.x + __uint_as_float(ru.x << 16)         + rb.x;
  float o1 = a1 + bb.y + __uint_as_float(ru.x & 0xFFFF0000u) + rb.y;
  float o2 = a2 + bb.z + __uint_as_float(ru.y << 16)         + rb.z;
  float o3 = a3 + bb.w + __uint_as_float(ru.y & 0xFFFF0000u) + rb.w;
  ushort4v o;
  o[0] = f2b(o0 > 0.f ? o0 : expf(o0) - 1.f);
  o[1] = f2b(o1 > 0.f ? o1 : expf(o1) - 1.f);
  o[2] = f2b(o2 > 0.f ? o2 : expf(o2) - 1.f);
  o[3] = f2b(o3 > 0.f ? o3 : expf(o3) - 1.f);
  *(ushort4v*)(h1b + (size_t)n*256 + c) = o;
}

// ---------------- layer1 logits (bf16 g1) ----------------
extern "C" __global__ void k_al1(const unsigned short* __restrict__ buf1b, const float* __restrict__ as1,
                                 const float* __restrict__ ad1, float* als1, float* ald1, int N){
  int n = blockIdx.x*4 + (threadIdx.x >> 6);
  if(n >= N) return;
  int lane = threadIdx.x & 63;
  float g = b2f(buf1b[(size_t)n*128 + lane]);
  float s = g*as1[lane], d = g*ad1[lane];
  #pragma unroll
  for(int o=32; o>0; o>>=1){ s += __shfl_xor(s,o); d += __shfl_xor(d,o); }
  if(lane == 0){ als1[n] = s; ald1[n] = d; }
}

// ---- gather layer1: fused LDS-alpha + pair-MLP gather + bias + residual + log_softmax ----
__launch_bounds__(256)
extern "C" __global__ void k_gather1(const unsigned short* __restrict__ buf1b,
                                     const float* __restrict__ als1, const float* __restrict__ ald1,
                                     const int* __restrict__ offs, const int* __restrict__ csr,
                                     const float* __restrict__ b1, const float* __restrict__ br1,
                                     float* __restrict__ out, int N){
  __shared__ float s_alpha[CH];
  __shared__ int   s_src[CH];
  __shared__ float s_den[1];
  __shared__ float smv[3][64];
  int n = blockIdx.x;
  int t = threadIdx.x;
  int lane = t & 63, w = t >> 6;
  int beg = offs[n], end = offs[n+1];
  float ald_n = ald1[n];

  if(t == 0) s_den[0] = 0.f;

  float acc = 0.f;

  for(int chunk = beg; chunk < end; chunk += CH){
    int m = end - chunk; if(m > CH) m = CH;
    __syncthreads();
    if(t < m){
      int s = csr[chunk + t];
      s_src[t] = s;
      float v = als1[s] + ald_n;
      v = v > 0.f ? v : NEG_SLOPE*v;
      float p = expf(v);
      s_alpha[t] = p;
      atomicAdd(&s_den[0], p);
    }
    __syncthreads();
    for(int base = w; base < m; base += 8){
      int ea = base, eb = base + 4;
      bool vb = eb < m;
      int sa = s_src[ea];
      int sb = vb ? s_src[eb] : sa;
      float pa = s_alpha[ea];
      float pb = vb ? s_alpha[eb] : 0.f;
      float fa = b2f(buf1b[(size_t)sa*128 + lane]);
      float fb = b2f(buf1b[(size_t)sb*128 + lane]);
      acc = fmaf(pa, fa, acc);
      acc = fmaf(pb, fb, acc);
    }
  }

  if(w != 0) smv[w-1][lane] = acc;
  __syncthreads();
  if(w != 0) return;
  #pragma unroll
  for(int jj=0; jj<3; jj++) acc += smv[jj][lane];
  acc *= 1.f/(s_den[0] + 1e-16f);

  float val = acc + b1[lane] + b2f(buf1b[(size_t)n*128 + 64 + lane]) + br1[lane];
  float mx = val;
  #pragma unroll
  for(int o=32; o>0; o>>=1) mx = fmaxf(mx, __shfl_xor(mx,o));
  float ex = expf(val - mx), smn = ex;
  #pragma unroll
  for(int o=32; o>0; o>>=1) smn += __shfl_xor(smn,o);
  out[(size_t)n*64 + lane] = val - mx - logf(smn);
}

// ---------------- launch ----------------
extern "C" void kernel_launch(void* const* d_in, const int* in_sizes, int n_in,
                              void* d_out, int out_size, void* d_ws, size_t ws_size,
                              hipStream_t stream){
  const float* x   = (const float*)d_in[0];
  const int*   ei  = (const int*)  d_in[1];
  const float* W0  = (const float*)d_in[2];
  const float* as0 = (const float*)d_in[3];
  const float* ad0 = (const float*)d_in[4];
  const float* b0  = (const float*)d_in[5];
  const float* Wr0 = (const float*)d_in[6];
  const float* br0 = (const float*)d_in[7];
  const float* W1  = (const float*)d_in[8];
  const float* as1 = (const float*)d_in[9];
  const float* ad1 = (const float*)d_in[10];
  const float* b1  = (const float*)d_in[11];
  const float* Wr1 = (const float*)d_in[12];
  const float* br1 = (const float*)d_in[13];
  int N = in_sizes[0] / 256;
  int E = in_sizes[1] / 2;
  const int* srcs = ei;
  const int* dsts = ei + E;
  float* out = (float*)d_out;

  // workspace layout (bf16 feature buffers)
  unsigned short* buf0b = (unsigned short*)d_ws;        // N*512 bf16 (h0 | r0)
  unsigned short* xb    = buf0b + (size_t)N*512;        // N*256 bf16 (dead after mgemm0)
  unsigned short* h1b   = xb    + (size_t)N*256;        // N*256 bf16
  unsigned short* buf1b = h1b   + (size_t)N*256;        // N*128 bf16 (g1 | r1)
  unsigned short* WT0   = buf1b + (size_t)N*128;        // 512*256 bf16
  unsigned short* WT1   = WT0   + 512*256;              // 128*256 bf16
  float*    als0 = (float*)(WT1 + 128*256);             // N*8
  float*    ald0 = als0 + (size_t)N*8;                  // N*8
  float*    als1 = ald0 + (size_t)N*8;                  // N
  float*    ald1 = als1 + N;                            // N
  int*      cnt  = (int*)(ald1 + N);                    // N (also cursor)
  int*      offs = cnt + N;                             // N+1
  int*      part = offs + N + 1;                        // 256
  int*      csr  = part + 256;                          // E+N

  int NB = (N + 255) / 256;
  int ET = E + N;

  // CSR build
  hipLaunchKernelGGL(k_init, dim3((N+255)/256), dim3(256), 0, stream, N, cnt);
  hipLaunchKernelGGL(k_count, dim3((E+255)/256), dim3(256), 0, stream, dsts, E, cnt);
  hipLaunchKernelGGL(k_scan_partial, dim3(NB), dim3(256), 0, stream, cnt, part, N);
  hipLaunchKernelGGL(k_scan_ex, dim3(1), dim3(256), 0, stream, part, NB);
  hipLaunchKernelGGL(k_scan_final, dim3(NB), dim3(256), 0, stream, cnt, part, offs, cnt, N);
  hipLaunchKernelGGL(k_scatter, dim3((ET+255)/256), dim3(256), 0, stream, srcs, dsts, E, N, cnt, csr);

  // casts / weight prep
  int n8 = N*256/8;
  hipLaunchKernelGGL(k_cast_x, dim3((n8+255)/256), dim3(256), 0, stream, x, xb, n8);
  hipLaunchKernelGGL(k_wt2, dim3((512*256+128*256+255)/256), dim3(256), 0, stream, W0, Wr0, W1, Wr1, WT0, WT1);

  int MB = (N + 127) / 128;
  // layer0: buf0b[N][512] = xb @ [W0|Wr0]
  hipLaunchKernelGGL(k_mgemm, dim3(4, MB), dim3(256), 0, stream, xb, WT0, buf0b, 512, N);
  hipLaunchKernelGGL(k_al0, dim3((N*8+255)/256), dim3(256), 0, stream, buf0b, as0, ad0, als0, ald0, N);
  hipLaunchKernelGGL(k_gather0, dim3(N), dim3(256), 0, stream, buf0b, als0, ald0, offs, csr, b0, br0, h1b, N);

  // layer1: buf1b[N][128] = h1b @ [W1|Wr1]
  hipLaunchKernelGGL(k_mgemm, dim3(1, MB), dim3(256), 0, stream, h1b, WT1, buf1b, 128, N);
  hipLaunchKernelGGL(k_al1, dim3((N+3)/4), dim3(256), 0, stream, buf1b, as1, ad1, als1, ald1, N);
  hipLaunchKernelGGL(k_gather1, dim3(N), dim3(256), 0, stream, buf1b, als1, ald1, offs, csr, b1, br1, out, N);
}

// Round 9
// 353.089 us; speedup vs baseline: 1.2971x; 1.0016x over previous
//
#include <hip/hip_runtime.h>
#include <math.h>

#define NEG_SLOPE 0.2f

typedef __attribute__((ext_vector_type(8))) short bf16x8;
typedef __attribute__((ext_vector_type(4))) float f32x4;
typedef __attribute__((ext_vector_type(8))) unsigned short ushort8;
typedef __attribute__((ext_vector_type(4))) unsigned short ushort4v;

__device__ __forceinline__ float b2f(unsigned short u){
  return __uint_as_float(((unsigned)u) << 16);
}
__device__ __forceinline__ unsigned short f2b(float f){
  unsigned u = __float_as_uint(f);
  return (unsigned short)((u + 0x7FFFu + ((u >> 16) & 1u)) >> 16);
}

// ---------------- init: cnt=1 (self loop) ----------------
extern "C" __global__ void k_init(int N, int* cnt){
  int n = blockIdx.x*blockDim.x + threadIdx.x;
  if(n < N) cnt[n] = 1;
}

// ---------------- CSR build ----------------
extern "C" __global__ void k_count(const int* __restrict__ dsts, int E, int* cnt){
  int e = blockIdx.x*blockDim.x + threadIdx.x;
  if(e >= E) return;
  atomicAdd(&cnt[dsts[e]], 1);
}

extern "C" __global__ void k_scan_partial(const int* __restrict__ cnt, int* part, int N){
  __shared__ int sh[256];
  int t = threadIdx.x, i = blockIdx.x*256 + t;
  sh[t] = (i < N) ? cnt[i] : 0;
  __syncthreads();
  for(int s=128; s>0; s>>=1){
    if(t < s) sh[t] += sh[t+s];
    __syncthreads();
  }
  if(t == 0) part[blockIdx.x] = sh[0];
}

extern "C" __global__ void k_scan_ex(int* part, int NB){
  __shared__ int sh[256];
  int t = threadIdx.x;
  int v = (t < NB) ? part[t] : 0;
  sh[t] = v; __syncthreads();
  for(int s=1; s<256; s<<=1){
    int u = (t >= s) ? sh[t-s] : 0;
    __syncthreads();
    sh[t] += u;
    __syncthreads();
  }
  if(t < NB) part[t] = sh[t] - v;  // exclusive
}

// also writes the scatter cursor (merged k_cursor)
extern "C" __global__ void k_scan_final(const int* __restrict__ cnt, const int* __restrict__ part,
                                        int* offs, int* cur, int N){
  __shared__ int sh[256];
  int t = threadIdx.x, i = blockIdx.x*256 + t;
  int v = (i < N) ? cnt[i] : 0;
  sh[t] = v; __syncthreads();
  for(int s=1; s<256; s<<=1){
    int u = (t >= s) ? sh[t-s] : 0;
    __syncthreads();
    sh[t] += u;
    __syncthreads();
  }
  int ex = part[blockIdx.x] + sh[t] - v;
  if(i < N){ offs[i] = ex; cur[i] = ex; }
  if(i == N-1) offs[N] = ex + v;
}

extern "C" __global__ void k_scatter(const int* __restrict__ srcs, const int* __restrict__ dsts,
                                     int E, int N, int* cur, int* csr){
  int i = blockIdx.x*blockDim.x + threadIdx.x;
  if(i >= E + N) return;
  int s, d;
  if(i < E){ s = srcs[i]; d = dsts[i]; } else { s = d = i - E; }
  int pos = atomicAdd(&cur[d], 1);
  csr[pos] = s;
}

// ---------------- fp32 -> bf16 cast (8 elems/thread) ----------------
extern "C" __global__ void k_cast_x(const float* __restrict__ x, unsigned short* __restrict__ xb, int n8){
  int i = blockIdx.x*blockDim.x + threadIdx.x;
  if(i >= n8) return;
  const float4* p = (const float4*)(x + (size_t)i*8);
  float4 v0 = p[0], v1 = p[1];
  ushort8 o;
  o[0]=f2b(v0.x); o[1]=f2b(v0.y); o[2]=f2b(v0.z); o[3]=f2b(v0.w);
  o[4]=f2b(v1.x); o[5]=f2b(v1.y); o[6]=f2b(v1.z); o[7]=f2b(v1.w);
  *(ushort8*)(xb + (size_t)i*8) = o;
}

// ---------------- weight transpose+concat (both layers, one launch) ----------------
extern "C" __global__ void k_wt2(const float* __restrict__ W0, const float* __restrict__ Wr0,
                                 const float* __restrict__ W1, const float* __restrict__ Wr1,
                                 unsigned short* __restrict__ WT0, unsigned short* __restrict__ WT1){
  int idx = blockIdx.x*256 + threadIdx.x;
  const int tot0 = 512*256;
  if(idx < tot0){
    int n = idx >> 8, k = idx & 255;
    const float* W = (n < 256) ? W0 : Wr0;
    int c = (n < 256) ? n : n - 256;
    WT0[idx] = f2b(W[(size_t)k*256 + c]);
  } else {
    idx -= tot0;
    if(idx >= 128*256) return;
    int n = idx >> 8, k = idx & 255;
    const float* W = (n < 64) ? W1 : Wr1;
    int c = (n < 64) ? n : n - 64;
    WT1[idx] = f2b(W[(size_t)k*64 + c]);
  }
}

// ---------------- bf16 MFMA GEMM: C[M][NC] = A[M][256] @ WT[NC][256]^T ----------------
__launch_bounds__(256)
extern "C" __global__ void k_mgemm(const unsigned short* __restrict__ A,
                                   const unsigned short* __restrict__ WT,
                                   unsigned short* __restrict__ C, int ldc, int M){
  __shared__ unsigned short As[128*64];
  __shared__ unsigned short Bs[128*64];
  int t = threadIdx.x;
  int lane = t & 63, wid = t >> 6;
  int wr = wid >> 1, wc = wid & 1;
  int row0 = blockIdx.y*128, col0 = blockIdx.x*128;
  f32x4 acc[4][4] = {};

  for(int k0 = 0; k0 < 256; k0 += 64){
    #pragma unroll
    for(int i=0; i<4; i++){
      int t2 = i*256 + t;
      int r = t2 >> 3;
      int dslot = (t2 & 7) ^ (r & 7);
      int gr = row0 + r; if(gr >= M) gr = M - 1;
      const unsigned short* ga = A + (size_t)gr*256 + k0 + dslot*8;
      __builtin_amdgcn_global_load_lds((const __attribute__((address_space(1))) unsigned*)ga,
          (__attribute__((address_space(3))) unsigned*)(As + i*2048 + wid*512), 16, 0, 0);
      const unsigned short* gb = WT + (size_t)(col0 + r)*256 + k0 + dslot*8;
      __builtin_amdgcn_global_load_lds((const __attribute__((address_space(1))) unsigned*)gb,
          (__attribute__((address_space(3))) unsigned*)(Bs + i*2048 + wid*512), 16, 0, 0);
    }
    __syncthreads();
    #pragma unroll
    for(int kc=0; kc<2; kc++){
      bf16x8 a[4], b[4];
      int kb = kc*4 + (lane >> 4);
      #pragma unroll
      for(int f=0; f<4; f++){
        int ar = wr*64 + f*16 + (lane & 15);
        a[f] = *(const bf16x8*)&As[ar*64 + ((kb ^ (ar & 7))*8)];
        int br = wc*64 + f*16 + (lane & 15);
        b[f] = *(const bf16x8*)&Bs[br*64 + ((kb ^ (br & 7))*8)];
      }
      #pragma unroll
      for(int fm=0; fm<4; fm++)
        #pragma unroll
        for(int fn=0; fn<4; fn++)
          acc[fm][fn] = __builtin_amdgcn_mfma_f32_16x16x32_bf16(a[fm], b[fn], acc[fm][fn], 0, 0, 0);
    }
    __syncthreads();
  }

  int rb = row0 + wr*64 + ((lane >> 4) << 2);
  int cb = col0 + wc*64 + (lane & 15);
  #pragma unroll
  for(int fm=0; fm<4; fm++){
    #pragma unroll
    for(int r=0; r<4; r++){
      int row = rb + fm*16 + r;
      if(row < M){
        #pragma unroll
        for(int fn=0; fn<4; fn++)
          C[(size_t)row*ldc + cb + fn*16] = f2b(acc[fm][fn][r]);
      }
    }
  }
}

// ---------------- attention logits layer0 (bf16 h0) ----------------
extern "C" __global__ void k_al0(const unsigned short* __restrict__ buf0b, const float* __restrict__ as0,
                                 const float* __restrict__ ad0, float* als0, float* ald0, int N){
  int i = blockIdx.x*blockDim.x + threadIdx.x;   // n*8+h
  if(i >= N*8) return;
  int n = i >> 3, h = i & 7;
  const uint4* hp = (const uint4*)(buf0b + (size_t)n*512 + h*32);
  const float* av = as0 + h*32;
  const float* dv = ad0 + h*32;
  float s = 0.f, d = 0.f;
  #pragma unroll
  for(int q=0; q<4; q++){
    uint4 u = hp[q];
    unsigned w[4] = {u.x, u.y, u.z, u.w};
    #pragma unroll
    for(int j=0; j<4; j++){
      float lo = __uint_as_float(w[j] << 16);
      float hi = __uint_as_float(w[j] & 0xFFFF0000u);
      int c = q*8 + j*2;
      s += lo*av[c] + hi*av[c+1];
      d += lo*dv[c] + hi*dv[c+1];
    }
  }
  als0[i] = s; ald0[i] = d;
}

// ---- gather layer0: fused LDS-alpha (chunked) + pair-MLP weighted gather ----
// block per node; lane owns channels c=lane*4..lane*4+3, head h=lane>>3.
// No max subtraction: logits are O(+-10) (unit-variance tensors), exp fp32-safe,
// softmax shift-invariant.
#define CH 64
__launch_bounds__(256)
extern "C" __global__ void k_gather0(const unsigned short* __restrict__ buf0b,
                                     const float* __restrict__ als0, const float* __restrict__ ald0,
                                     const int* __restrict__ offs, const int* __restrict__ csr,
                                     const float* __restrict__ b0, const float* __restrict__ br0,
                                     unsigned short* __restrict__ h1b, int N){
  __shared__ float s_alpha[CH][8];
  __shared__ int   s_src[CH];
  __shared__ float s_den[8];
  __shared__ float4 smv[3][64];
  int n = blockIdx.x;
  int t = threadIdx.x;
  int lane = t & 63, w = t >> 6;
  int h = lane >> 3;
  int c = lane*4;
  int beg = offs[n], end = offs[n+1];
  int hh = t & 7;                       // head this thread computes alpha for
  float ald_n = ald0[n*8 + hh];

  if(t < 8) s_den[t] = 0.f;

  float a0=0.f, a1=0.f, a2=0.f, a3=0.f;

  for(int chunk = beg; chunk < end; chunk += CH){
    int m = end - chunk; if(m > CH) m = CH;
    __syncthreads();                    // den-init visible / prev phase B done
    // phase A: alpha for m edges x 8 heads (each computed exactly once)
    for(int idx = t; idx < m*8; idx += 256){
      int e = idx >> 3;
      int s = csr[chunk + e];
      if(hh == 0) s_src[e] = s;
      float v = als0[s*8 + hh] + ald_n;
      v = v > 0.f ? v : NEG_SLOPE*v;
      float p = expf(v);
      s_alpha[e][hh] = p;
      atomicAdd(&s_den[hh], p);
    }
    __syncthreads();
    // phase B: pair-wise gather (2 feature loads in flight per wave)
    for(int base = w; base < m; base += 8){
      int ea = base, eb = base + 4;
      bool vb = eb < m;
      int sa = s_src[ea];
      int sb = vb ? s_src[eb] : sa;
      float pa = s_alpha[ea][h];
      float pb = vb ? s_alpha[eb][h] : 0.f;
      uint2 ua = *(const uint2*)(buf0b + (size_t)sa*512 + c);
      uint2 ub = *(const uint2*)(buf0b + (size_t)sb*512 + c);
      a0 = fmaf(pa, __uint_as_float(ua.x << 16),         a0);
      a1 = fmaf(pa, __uint_as_float(ua.x & 0xFFFF0000u), a1);
      a2 = fmaf(pa, __uint_as_float(ua.y << 16),         a2);
      a3 = fmaf(pa, __uint_as_float(ua.y & 0xFFFF0000u), a3);
      a0 = fmaf(pb, __uint_as_float(ub.x << 16),         a0);
      a1 = fmaf(pb, __uint_as_float(ub.x & 0xFFFF0000u), a1);
      a2 = fmaf(pb, __uint_as_float(ub.y << 16),         a2);
      a3 = fmaf(pb, __uint_as_float(ub.y & 0xFFFF0000u), a3);
    }
  }

  if(w != 0){
    float4 v; v.x=a0; v.y=a1; v.z=a2; v.w=a3;
    smv[w-1][lane] = v;
  }
  __syncthreads();
  if(w != 0) return;
  #pragma unroll
  for(int jj=0; jj<3; jj++){
    float4 v = smv[jj][lane];
    a0 += v.x; a1 += v.y; a2 += v.z; a3 += v.w;
  }
  float rden = 1.f/(s_den[h] + 1e-16f);
  a0 *= rden; a1 *= rden; a2 *= rden; a3 *= rden;

  float4 bb = *(const float4*)(b0 + c);
  float4 rb = *(const float4*)(br0 + c);
  uint2 ru = *(const uint2*)(buf0b + (size_t)n*512 + 256 + c);
  float o0 = a0 + bb.x + __uint_as_float(ru.x << 16)         + rb.x;
  float o1 = a1 + bb.y + __uint_as_float(ru.x & 0xFFFF0000u) + rb.y;
  float o2 = a2 + bb.z + __uint_as_float(ru.y << 16)         + rb.z;
  float o3 = a3 + bb.w + __uint_as_float(ru.y & 0xFFFF0000u) + rb.w;
  ushort4v o;
  o[0] = f2b(o0 > 0.f ? o0 : expf(o0) - 1.f);
  o[1] = f2b(o1 > 0.f ? o1 : expf(o1) - 1.f);
  o[2] = f2b(o2 > 0.f ? o2 : expf(o2) - 1.f);
  o[3] = f2b(o3 > 0.f ? o3 : expf(o3) - 1.f);
  *(ushort4v*)(h1b + (size_t)n*256 + c) = o;
}

// ---------------- layer1 logits (bf16 g1) ----------------
extern "C" __global__ void k_al1(const unsigned short* __restrict__ buf1b, const float* __restrict__ as1,
                                 const float* __restrict__ ad1, float* als1, float* ald1, int N){
  int n = blockIdx.x*4 + (threadIdx.x >> 6);
  if(n >= N) return;
  int lane = threadIdx.x & 63;
  float g = b2f(buf1b[(size_t)n*128 + lane]);
  float s = g*as1[lane], d = g*ad1[lane];
  #pragma unroll
  for(int o=32; o>0; o>>=1){ s += __shfl_xor(s,o); d += __shfl_xor(d,o); }
  if(lane == 0){ als1[n] = s; ald1[n] = d; }
}

// ---- gather layer1: fused LDS-alpha + pair-MLP gather + bias + residual + log_softmax ----
__launch_bounds__(256)
extern "C" __global__ void k_gather1(const unsigned short* __restrict__ buf1b,
                                     const float* __restrict__ als1, const float* __restrict__ ald1,
                                     const int* __restrict__ offs, const int* __restrict__ csr,
                                     const float* __restrict__ b1, const float* __restrict__ br1,
                                     float* __restrict__ out, int N){
  __shared__ float s_alpha[CH];
  __shared__ int   s_src[CH];
  __shared__ float s_den[1];
  __shared__ float smv[3][64];
  int n = blockIdx.x;
  int t = threadIdx.x;
  int lane = t & 63, w = t >> 6;
  int beg = offs[n], end = offs[n+1];
  float ald_n = ald1[n];

  if(t == 0) s_den[0] = 0.f;

  float acc = 0.f;

  for(int chunk = beg; chunk < end; chunk += CH){
    int m = end - chunk; if(m > CH) m = CH;
    __syncthreads();
    if(t < m){
      int s = csr[chunk + t];
      s_src[t] = s;
      float v = als1[s] + ald_n;
      v = v > 0.f ? v : NEG_SLOPE*v;
      float p = expf(v);
      s_alpha[t] = p;
      atomicAdd(&s_den[0], p);
    }
    __syncthreads();
    for(int base = w; base < m; base += 8){
      int ea = base, eb = base + 4;
      bool vb = eb < m;
      int sa = s_src[ea];
      int sb = vb ? s_src[eb] : sa;
      float pa = s_alpha[ea];
      float pb = vb ? s_alpha[eb] : 0.f;
      float fa = b2f(buf1b[(size_t)sa*128 + lane]);
      float fb = b2f(buf1b[(size_t)sb*128 + lane]);
      acc = fmaf(pa, fa, acc);
      acc = fmaf(pb, fb, acc);
    }
  }

  if(w != 0) smv[w-1][lane] = acc;
  __syncthreads();
  if(w != 0) return;
  #pragma unroll
  for(int jj=0; jj<3; jj++) acc += smv[jj][lane];
  acc *= 1.f/(s_den[0] + 1e-16f);

  float val = acc + b1[lane] + b2f(buf1b[(size_t)n*128 + 64 + lane]) + br1[lane];
  float mx = val;
  #pragma unroll
  for(int o=32; o>0; o>>=1) mx = fmaxf(mx, __shfl_xor(mx,o));
  float ex = expf(val - mx), smn = ex;
  #pragma unroll
  for(int o=32; o>0; o>>=1) smn += __shfl_xor(smn,o);
  out[(size_t)n*64 + lane] = val - mx - logf(smn);
}

// ---------------- launch ----------------
extern "C" void kernel_launch(void* const* d_in, const int* in_sizes, int n_in,
                              void* d_out, int out_size, void* d_ws, size_t ws_size,
                              hipStream_t stream){
  const float* x   = (const float*)d_in[0];
  const int*   ei  = (const int*)  d_in[1];
  const float* W0  = (const float*)d_in[2];
  const float* as0 = (const float*)d_in[3];
  const float* ad0 = (const float*)d_in[4];
  const float* b0  = (const float*)d_in[5];
  const float* Wr0 = (const float*)d_in[6];
  const float* br0 = (const float*)d_in[7];
  const float* W1  = (const float*)d_in[8];
  const float* as1 = (const float*)d_in[9];
  const float* ad1 = (const float*)d_in[10];
  const float* b1  = (const float*)d_in[11];
  const float* Wr1 = (const float*)d_in[12];
  const float* br1 = (const float*)d_in[13];
  int N = in_sizes[0] / 256;
  int E = in_sizes[1] / 2;
  const int* srcs = ei;
  const int* dsts = ei + E;
  float* out = (float*)d_out;

  // workspace layout (bf16 feature buffers)
  unsigned short* buf0b = (unsigned short*)d_ws;        // N*512 bf16 (h0 | r0)
  unsigned short* xb    = buf0b + (size_t)N*512;        // N*256 bf16 (dead after mgemm0)
  unsigned short* h1b   = xb    + (size_t)N*256;        // N*256 bf16
  unsigned short* buf1b = h1b   + (size_t)N*256;        // N*128 bf16 (g1 | r1)
  unsigned short* WT0   = buf1b + (size_t)N*128;        // 512*256 bf16
  unsigned short* WT1   = WT0   + 512*256;              // 128*256 bf16
  float*    als0 = (float*)(WT1 + 128*256);             // N*8
  float*    ald0 = als0 + (size_t)N*8;                  // N*8
  float*    als1 = ald0 + (size_t)N*8;                  // N
  float*    ald1 = als1 + N;                            // N
  int*      cnt  = (int*)(ald1 + N);                    // N (also cursor)
  int*      offs = cnt + N;                             // N+1
  int*      part = offs + N + 1;                        // 256
  int*      csr  = part + 256;                          // E+N

  int NB = (N + 255) / 256;
  int ET = E + N;

  // CSR build
  hipLaunchKernelGGL(k_init, dim3((N+255)/256), dim3(256), 0, stream, N, cnt);
  hipLaunchKernelGGL(k_count, dim3((E+255)/256), dim3(256), 0, stream, dsts, E, cnt);
  hipLaunchKernelGGL(k_scan_partial, dim3(NB), dim3(256), 0, stream, cnt, part, N);
  hipLaunchKernelGGL(k_scan_ex, dim3(1), dim3(256), 0, stream, part, NB);
  hipLaunchKernelGGL(k_scan_final, dim3(NB), dim3(256), 0, stream, cnt, part, offs, cnt, N);
  hipLaunchKernelGGL(k_scatter, dim3((ET+255)/256), dim3(256), 0, stream, srcs, dsts, E, N, cnt, csr);

  // casts / weight prep
  int n8 = N*256/8;
  hipLaunchKernelGGL(k_cast_x, dim3((n8+255)/256), dim3(256), 0, stream, x, xb, n8);
  hipLaunchKernelGGL(k_wt2, dim3((512*256+128*256+255)/256), dim3(256), 0, stream, W0, Wr0, W1, Wr1, WT0, WT1);

  int MB = (N + 127) / 128;
  // layer0: buf0b[N][512] = xb @ [W0|Wr0]
  hipLaunchKernelGGL(k_mgemm, dim3(4, MB), dim3(256), 0, stream, xb, WT0, buf0b, 512, N);
  hipLaunchKernelGGL(k_al0, dim3((N*8+255)/256), dim3(256), 0, stream, buf0b, as0, ad0, als0, ald0, N);
  hipLaunchKernelGGL(k_gather0, dim3(N), dim3(256), 0, stream, buf0b, als0, ald0, offs, csr, b0, br0, h1b, N);

  // layer1: buf1b[N][128] = h1b @ [W1|Wr1]
  hipLaunchKernelGGL(k_mgemm, dim3(1, MB), dim3(256), 0, stream, h1b, WT1, buf1b, 128, N);
  hipLaunchKernelGGL(k_al1, dim3((N+3)/4), dim3(256), 0, stream, buf1b, as1, ad1, als1, ald1, N);
  hipLaunchKernelGGL(k_gather1, dim3(N), dim3(256), 0, stream, buf1b, als1, ald1, offs, csr, b1, br1, out, N);
}

// Round 10
// 339.899 us; speedup vs baseline: 1.3475x; 1.0388x over previous
//
#include <hip/hip_runtime.h>
#include <math.h>

#define NEG_SLOPE 0.2f

typedef __attribute__((ext_vector_type(8))) short bf16x8;
typedef __attribute__((ext_vector_type(4))) float f32x4;
typedef __attribute__((ext_vector_type(8))) unsigned short ushort8;
typedef __attribute__((ext_vector_type(4))) unsigned short ushort4v;

__device__ __forceinline__ float b2f(unsigned short u){
  return __uint_as_float(((unsigned)u) << 16);
}
__device__ __forceinline__ unsigned short f2b(float f){
  unsigned u = __float_as_uint(f);
  return (unsigned short)((u + 0x7FFFu + ((u >> 16) & 1u)) >> 16);
}

// ---------------- init: cnt=1 (self loop) ----------------
extern "C" __global__ void k_init(int N, int* cnt){
  int n = blockIdx.x*blockDim.x + threadIdx.x;
  if(n < N) cnt[n] = 1;
}

// ---------------- CSR build ----------------
extern "C" __global__ void k_count(const int* __restrict__ dsts, int E, int* cnt){
  int e = blockIdx.x*blockDim.x + threadIdx.x;
  if(e >= E) return;
  atomicAdd(&cnt[dsts[e]], 1);
}

extern "C" __global__ void k_scan_partial(const int* __restrict__ cnt, int* part, int N){
  __shared__ int sh[256];
  int t = threadIdx.x, i = blockIdx.x*256 + t;
  sh[t] = (i < N) ? cnt[i] : 0;
  __syncthreads();
  for(int s=128; s>0; s>>=1){
    if(t < s) sh[t] += sh[t+s];
    __syncthreads();
  }
  if(t == 0) part[blockIdx.x] = sh[0];
}

extern "C" __global__ void k_scan_ex(int* part, int NB){
  __shared__ int sh[256];
  int t = threadIdx.x;
  int v = (t < NB) ? part[t] : 0;
  sh[t] = v; __syncthreads();
  for(int s=1; s<256; s<<=1){
    int u = (t >= s) ? sh[t-s] : 0;
    __syncthreads();
    sh[t] += u;
    __syncthreads();
  }
  if(t < NB) part[t] = sh[t] - v;  // exclusive
}

// also writes the scatter cursor (merged k_cursor)
extern "C" __global__ void k_scan_final(const int* __restrict__ cnt, const int* __restrict__ part,
                                        int* offs, int* cur, int N){
  __shared__ int sh[256];
  int t = threadIdx.x, i = blockIdx.x*256 + t;
  int v = (i < N) ? cnt[i] : 0;
  sh[t] = v; __syncthreads();
  for(int s=1; s<256; s<<=1){
    int u = (t >= s) ? sh[t-s] : 0;
    __syncthreads();
    sh[t] += u;
    __syncthreads();
  }
  int ex = part[blockIdx.x] + sh[t] - v;
  if(i < N){ offs[i] = ex; cur[i] = ex; }
  if(i == N-1) offs[N] = ex + v;
}

extern "C" __global__ void k_scatter(const int* __restrict__ srcs, const int* __restrict__ dsts,
                                     int E, int N, int* cur, int* csr){
  int i = blockIdx.x*blockDim.x + threadIdx.x;
  if(i >= E + N) return;
  int s, d;
  if(i < E){ s = srcs[i]; d = dsts[i]; } else { s = d = i - E; }
  int pos = atomicAdd(&cur[d], 1);
  csr[pos] = s;
}

// ---------------- fp32 -> bf16 cast (8 elems/thread) ----------------
extern "C" __global__ void k_cast_x(const float* __restrict__ x, unsigned short* __restrict__ xb, int n8){
  int i = blockIdx.x*blockDim.x + threadIdx.x;
  if(i >= n8) return;
  const float4* p = (const float4*)(x + (size_t)i*8);
  float4 v0 = p[0], v1 = p[1];
  ushort8 o;
  o[0]=f2b(v0.x); o[1]=f2b(v0.y); o[2]=f2b(v0.z); o[3]=f2b(v0.w);
  o[4]=f2b(v1.x); o[5]=f2b(v1.y); o[6]=f2b(v1.z); o[7]=f2b(v1.w);
  *(ushort8*)(xb + (size_t)i*8) = o;
}

// ---------------- weight transpose+concat (both layers, one launch) ----------------
extern "C" __global__ void k_wt2(const float* __restrict__ W0, const float* __restrict__ Wr0,
                                 const float* __restrict__ W1, const float* __restrict__ Wr1,
                                 unsigned short* __restrict__ WT0, unsigned short* __restrict__ WT1){
  int idx = blockIdx.x*256 + threadIdx.x;
  const int tot0 = 512*256;
  if(idx < tot0){
    int n = idx >> 8, k = idx & 255;
    const float* W = (n < 256) ? W0 : Wr0;
    int c = (n < 256) ? n : n - 256;
    WT0[idx] = f2b(W[(size_t)k*256 + c]);
  } else {
    idx -= tot0;
    if(idx >= 128*256) return;
    int n = idx >> 8, k = idx & 255;
    const float* W = (n < 64) ? W1 : Wr1;
    int c = (n < 64) ? n : n - 64;
    WT1[idx] = f2b(W[(size_t)k*64 + c]);
  }
}

// ---------------- bf16 MFMA GEMM: C[M][NC] = A[M][256] @ WT[NC][256]^T ----------------
// 1-D grid; for NCB=4 the 4 col-blocks of a row-tile get linear ids differing by 8
// (same XCD under round-robin dispatch) so the shared A tile stays in that XCD's L2.
__launch_bounds__(256)
extern "C" __global__ void k_mgemm(const unsigned short* __restrict__ A,
                                   const unsigned short* __restrict__ WT,
                                   unsigned short* __restrict__ C, int ldc, int M,
                                   int MB, int NCB){
  int id = blockIdx.x;
  int row_blk, col_blk;
  if(NCB == 4){
    int group = id >> 5;            // 32 blocks = 8 row-tiles x 4 col-tiles
    int r8 = id & 7;
    col_blk = (id >> 3) & 3;
    row_blk = group*8 + r8;
  } else {
    row_blk = id; col_blk = 0;
  }
  if(row_blk >= MB) return;

  __shared__ unsigned short As[128*64];
  __shared__ unsigned short Bs[128*64];
  int t = threadIdx.x;
  int lane = t & 63, wid = t >> 6;
  int wr = wid >> 1, wc = wid & 1;
  int row0 = row_blk*128, col0 = col_blk*128;
  f32x4 acc[4][4] = {};

  for(int k0 = 0; k0 < 256; k0 += 64){
    #pragma unroll
    for(int i=0; i<4; i++){
      int t2 = i*256 + t;
      int r = t2 >> 3;
      int dslot = (t2 & 7) ^ (r & 7);
      int gr = row0 + r; if(gr >= M) gr = M - 1;
      const unsigned short* ga = A + (size_t)gr*256 + k0 + dslot*8;
      __builtin_amdgcn_global_load_lds((const __attribute__((address_space(1))) unsigned*)ga,
          (__attribute__((address_space(3))) unsigned*)(As + i*2048 + wid*512), 16, 0, 0);
      const unsigned short* gb = WT + (size_t)(col0 + r)*256 + k0 + dslot*8;
      __builtin_amdgcn_global_load_lds((const __attribute__((address_space(1))) unsigned*)gb,
          (__attribute__((address_space(3))) unsigned*)(Bs + i*2048 + wid*512), 16, 0, 0);
    }
    __syncthreads();
    #pragma unroll
    for(int kc=0; kc<2; kc++){
      bf16x8 a[4], b[4];
      int kb = kc*4 + (lane >> 4);
      #pragma unroll
      for(int f=0; f<4; f++){
        int ar = wr*64 + f*16 + (lane & 15);
        a[f] = *(const bf16x8*)&As[ar*64 + ((kb ^ (ar & 7))*8)];
        int br = wc*64 + f*16 + (lane & 15);
        b[f] = *(const bf16x8*)&Bs[br*64 + ((kb ^ (br & 7))*8)];
      }
      #pragma unroll
      for(int fm=0; fm<4; fm++)
        #pragma unroll
        for(int fn=0; fn<4; fn++)
          acc[fm][fn] = __builtin_amdgcn_mfma_f32_16x16x32_bf16(a[fm], b[fn], acc[fm][fn], 0, 0, 0);
    }
    __syncthreads();
  }

  int rb = row0 + wr*64 + ((lane >> 4) << 2);
  int cb = col0 + wc*64 + (lane & 15);
  #pragma unroll
  for(int fm=0; fm<4; fm++){
    #pragma unroll
    for(int r=0; r<4; r++){
      int row = rb + fm*16 + r;
      if(row < M){
        #pragma unroll
        for(int fn=0; fn<4; fn++)
          C[(size_t)row*ldc + cb + fn*16] = f2b(acc[fm][fn][r]);
      }
    }
  }
}

// ---------------- attention logits layer0 (bf16 h0) ----------------
extern "C" __global__ void k_al0(const unsigned short* __restrict__ buf0b, const float* __restrict__ as0,
                                 const float* __restrict__ ad0, float* als0, float* ald0, int N){
  int i = blockIdx.x*blockDim.x + threadIdx.x;   // n*8+h
  if(i >= N*8) return;
  int n = i >> 3, h = i & 7;
  const uint4* hp = (const uint4*)(buf0b + (size_t)n*512 + h*32);
  const float* av = as0 + h*32;
  const float* dv = ad0 + h*32;
  float s = 0.f, d = 0.f;
  #pragma unroll
  for(int q=0; q<4; q++){
    uint4 u = hp[q];
    unsigned w[4] = {u.x, u.y, u.z, u.w};
    #pragma unroll
    for(int j=0; j<4; j++){
      float lo = __uint_as_float(w[j] << 16);
      float hi = __uint_as_float(w[j] & 0xFFFF0000u);
      int c = q*8 + j*2;
      s += lo*av[c] + hi*av[c+1];
      d += lo*dv[c] + hi*dv[c+1];
    }
  }
  als0[i] = s; ald0[i] = d;
}

// ---- gather layer0: fused LDS-alpha (chunked) + 4-wide MLP weighted gather ----
// block per node; lane owns channels c=lane*4..lane*4+3, head h=lane>>3.
// No max subtraction: logits are O(+-10) (unit-variance tensors), exp fp32-safe,
// softmax shift-invariant.
#define CH 64
__launch_bounds__(256)
extern "C" __global__ void k_gather0(const unsigned short* __restrict__ buf0b,
                                     const float* __restrict__ als0, const float* __restrict__ ald0,
                                     const int* __restrict__ offs, const int* __restrict__ csr,
                                     const float* __restrict__ b0, const float* __restrict__ br0,
                                     unsigned short* __restrict__ h1b, int N){
  __shared__ float s_alpha[CH][8];
  __shared__ int   s_src[CH];
  __shared__ float s_den[8];
  __shared__ float4 smv[3][64];
  int n = blockIdx.x;
  int t = threadIdx.x;
  int lane = t & 63, w = t >> 6;
  int h = lane >> 3;
  int c = lane*4;
  int beg = offs[n], end = offs[n+1];
  int hh = t & 7;                       // head this thread computes alpha for
  float ald_n = ald0[n*8 + hh];

  if(t < 8) s_den[t] = 0.f;

  float a0=0.f, a1=0.f, a2=0.f, a3=0.f;

  for(int chunk = beg; chunk < end; chunk += CH){
    int m = end - chunk; if(m > CH) m = CH;
    __syncthreads();                    // den-init visible / prev phase B done
    // phase A: alpha for m edges x 8 heads (each computed exactly once)
    float dpart = 0.f;
    for(int idx = t; idx < m*8; idx += 256){
      int e = idx >> 3;
      int s = csr[chunk + e];
      if(hh == 0) s_src[e] = s;
      float v = als0[s*8 + hh] + ald_n;
      v = v > 0.f ? v : NEG_SLOPE*v;
      float p = expf(v);
      s_alpha[e][hh] = p;
      dpart += p;
    }
    // sum over lanes sharing hh within the wave (lanes l, l^8, l^16, l^32)
    dpart += __shfl_xor(dpart, 8);
    dpart += __shfl_xor(dpart, 16);
    dpart += __shfl_xor(dpart, 32);
    if(lane < 8) atomicAdd(&s_den[lane], dpart);   // 8 atomics per wave
    __syncthreads();
    // phase B: 4 edges per wave-iteration, all loads issued before the FMAs
    for(int base = w*4; base < m; base += 16){
      int e1 = base+1, e2 = base+2, e3 = base+3;
      int s0 = s_src[base];
      int s1 = (e1 < m) ? s_src[e1] : s0;
      int s2 = (e2 < m) ? s_src[e2] : s0;
      int s3 = (e3 < m) ? s_src[e3] : s0;
      float p0 = s_alpha[base][h];
      float p1 = (e1 < m) ? s_alpha[e1][h] : 0.f;
      float p2 = (e2 < m) ? s_alpha[e2][h] : 0.f;
      float p3 = (e3 < m) ? s_alpha[e3][h] : 0.f;
      uint2 u0 = *(const uint2*)(buf0b + (size_t)s0*512 + c);
      uint2 u1 = *(const uint2*)(buf0b + (size_t)s1*512 + c);
      uint2 u2 = *(const uint2*)(buf0b + (size_t)s2*512 + c);
      uint2 u3 = *(const uint2*)(buf0b + (size_t)s3*512 + c);
      a0 = fmaf(p0, __uint_as_float(u0.x << 16),         a0);
      a1 = fmaf(p0, __uint_as_float(u0.x & 0xFFFF0000u), a1);
      a2 = fmaf(p0, __uint_as_float(u0.y << 16),         a2);
      a3 = fmaf(p0, __uint_as_float(u0.y & 0xFFFF0000u), a3);
      a0 = fmaf(p1, __uint_as_float(u1.x << 16),         a0);
      a1 = fmaf(p1, __uint_as_float(u1.x & 0xFFFF0000u), a1);
      a2 = fmaf(p1, __uint_as_float(u1.y << 16),         a2);
      a3 = fmaf(p1, __uint_as_float(u1.y & 0xFFFF0000u), a3);
      a0 = fmaf(p2, __uint_as_float(u2.x << 16),         a0);
      a1 = fmaf(p2, __uint_as_float(u2.x & 0xFFFF0000u), a1);
      a2 = fmaf(p2, __uint_as_float(u2.y << 16),         a2);
      a3 = fmaf(p2, __uint_as_float(u2.y & 0xFFFF0000u), a3);
      a0 = fmaf(p3, __uint_as_float(u3.x << 16),         a0);
      a1 = fmaf(p3, __uint_as_float(u3.x & 0xFFFF0000u), a1);
      a2 = fmaf(p3, __uint_as_float(u3.y << 16),         a2);
      a3 = fmaf(p3, __uint_as_float(u3.y & 0xFFFF0000u), a3);
    }
  }

  if(w != 0){
    float4 v; v.x=a0; v.y=a1; v.z=a2; v.w=a3;
    smv[w-1][lane] = v;
  }
  __syncthreads();
  if(w != 0) return;
  #pragma unroll
  for(int jj=0; jj<3; jj++){
    float4 v = smv[jj][lane];
    a0 += v.x; a1 += v.y; a2 += v.z; a3 += v.w;
  }
  float rden = 1.f/(s_den[h] + 1e-16f);
  a0 *= rden; a1 *= rden; a2 *= rden; a3 *= rden;

  float4 bb = *(const float4*)(b0 + c);
  float4 rb = *(const float4*)(br0 + c);
  uint2 ru = *(const uint2*)(buf0b + (size_t)n*512 + 256 + c);
  float o0 = a0 + bb.x + __uint_as_float(ru.x << 16)         + rb.x;
  float o1 = a1 + bb.y + __uint_as_float(ru.x & 0xFFFF0000u) + rb.y;
  float o2 = a2 + bb.z + __uint_as_float(ru.y << 16)         + rb.z;
  float o3 = a3 + bb.w + __uint_as_float(ru.y & 0xFFFF0000u) + rb.w;
  ushort4v o;
  o[0] = f2b(o0 > 0.f ? o0 : expf(o0) - 1.f);
  o[1] = f2b(o1 > 0.f ? o1 : expf(o1) - 1.f);
  o[2] = f2b(o2 > 0.f ? o2 : expf(o2) - 1.f);
  o[3] = f2b(o3 > 0.f ? o3 : expf(o3) - 1.f);
  *(ushort4v*)(h1b + (size_t)n*256 + c) = o;
}

// ---------------- layer1 logits (bf16 g1) ----------------
extern "C" __global__ void k_al1(const unsigned short* __restrict__ buf1b, const float* __restrict__ as1,
                                 const float* __restrict__ ad1, float* als1, float* ald1, int N){
  int n = blockIdx.x*4 + (threadIdx.x >> 6);
  if(n >= N) return;
  int lane = threadIdx.x & 63;
  float g = b2f(buf1b[(size_t)n*128 + lane]);
  float s = g*as1[lane], d = g*ad1[lane];
  #pragma unroll
  for(int o=32; o>0; o>>=1){ s += __shfl_xor(s,o); d += __shfl_xor(d,o); }
  if(lane == 0){ als1[n] = s; ald1[n] = d; }
}

// ---- gather layer1: fused LDS-alpha + 4-wide gather + bias + residual + log_softmax ----
__launch_bounds__(256)
extern "C" __global__ void k_gather1(const unsigned short* __restrict__ buf1b,
                                     const float* __restrict__ als1, const float* __restrict__ ald1,
                                     const int* __restrict__ offs, const int* __restrict__ csr,
                                     const float* __restrict__ b1, const float* __restrict__ br1,
                                     float* __restrict__ out, int N){
  __shared__ float s_alpha[CH];
  __shared__ int   s_src[CH];
  __shared__ float s_den[1];
  __shared__ float smv[3][64];
  int n = blockIdx.x;
  int t = threadIdx.x;
  int lane = t & 63, w = t >> 6;
  int beg = offs[n], end = offs[n+1];
  float ald_n = ald1[n];

  if(t == 0) s_den[0] = 0.f;

  float acc = 0.f;

  for(int chunk = beg; chunk < end; chunk += CH){
    int m = end - chunk; if(m > CH) m = CH;
    __syncthreads();
    float dpart = 0.f;
    if(t < m){
      int s = csr[chunk + t];
      s_src[t] = s;
      float v = als1[s] + ald_n;
      v = v > 0.f ? v : NEG_SLOPE*v;
      float p = expf(v);
      s_alpha[t] = p;
      dpart = p;
    }
    #pragma unroll
    for(int o=32; o>0; o>>=1) dpart += __shfl_xor(dpart, o);
    if(lane == 0 && w == 0) atomicAdd(&s_den[0], dpart);
    __syncthreads();
    for(int base = w*4; base < m; base += 16){
      int e1 = base+1, e2 = base+2, e3 = base+3;
      int s0 = s_src[base];
      int s1 = (e1 < m) ? s_src[e1] : s0;
      int s2 = (e2 < m) ? s_src[e2] : s0;
      int s3 = (e3 < m) ? s_src[e3] : s0;
      float p0 = s_alpha[base];
      float p1 = (e1 < m) ? s_alpha[e1] : 0.f;
      float p2 = (e2 < m) ? s_alpha[e2] : 0.f;
      float p3 = (e3 < m) ? s_alpha[e3] : 0.f;
      unsigned short f0 = buf1b[(size_t)s0*128 + lane];
      unsigned short f1 = buf1b[(size_t)s1*128 + lane];
      unsigned short f2 = buf1b[(size_t)s2*128 + lane];
      unsigned short f3 = buf1b[(size_t)s3*128 + lane];
      acc = fmaf(p0, b2f(f0), acc);
      acc = fmaf(p1, b2f(f1), acc);
      acc = fmaf(p2, b2f(f2), acc);
      acc = fmaf(p3, b2f(f3), acc);
    }
  }

  if(w != 0) smv[w-1][lane] = acc;
  __syncthreads();
  if(w != 0) return;
  #pragma unroll
  for(int jj=0; jj<3; jj++) acc += smv[jj][lane];
  acc *= 1.f/(s_den[0] + 1e-16f);

  float val = acc + b1[lane] + b2f(buf1b[(size_t)n*128 + 64 + lane]) + br1[lane];
  float mx = val;
  #pragma unroll
  for(int o=32; o>0; o>>=1) mx = fmaxf(mx, __shfl_xor(mx,o));
  float ex = expf(val - mx), smn = ex;
  #pragma unroll
  for(int o=32; o>0; o>>=1) smn += __shfl_xor(smn,o);
  out[(size_t)n*64 + lane] = val - mx - logf(smn);
}

// ---------------- launch ----------------
extern "C" void kernel_launch(void* const* d_in, const int* in_sizes, int n_in,
                              void* d_out, int out_size, void* d_ws, size_t ws_size,
                              hipStream_t stream){
  const float* x   = (const float*)d_in[0];
  const int*   ei  = (const int*)  d_in[1];
  const float* W0  = (const float*)d_in[2];
  const float* as0 = (const float*)d_in[3];
  const float* ad0 = (const float*)d_in[4];
  const float* b0  = (const float*)d_in[5];
  const float* Wr0 = (const float*)d_in[6];
  const float* br0 = (const float*)d_in[7];
  const float* W1  = (const float*)d_in[8];
  const float* as1 = (const float*)d_in[9];
  const float* ad1 = (const float*)d_in[10];
  const float* b1  = (const float*)d_in[11];
  const float* Wr1 = (const float*)d_in[12];
  const float* br1 = (const float*)d_in[13];
  int N = in_sizes[0] / 256;
  int E = in_sizes[1] / 2;
  const int* srcs = ei;
  const int* dsts = ei + E;
  float* out = (float*)d_out;

  // workspace layout (bf16 feature buffers)
  unsigned short* buf0b = (unsigned short*)d_ws;        // N*512 bf16 (h0 | r0)
  unsigned short* xb    = buf0b + (size_t)N*512;        // N*256 bf16 (dead after mgemm0)
  unsigned short* h1b   = xb    + (size_t)N*256;        // N*256 bf16
  unsigned short* buf1b = h1b   + (size_t)N*256;        // N*128 bf16 (g1 | r1)
  unsigned short* WT0   = buf1b + (size_t)N*128;        // 512*256 bf16
  unsigned short* WT1   = WT0   + 512*256;              // 128*256 bf16
  float*    als0 = (float*)(WT1 + 128*256);             // N*8
  float*    ald0 = als0 + (size_t)N*8;                  // N*8
  float*    als1 = ald0 + (size_t)N*8;                  // N
  float*    ald1 = als1 + N;                            // N
  int*      cnt  = (int*)(ald1 + N);                    // N (also cursor)
  int*      offs = cnt + N;                             // N+1
  int*      part = offs + N + 1;                        // 256
  int*      csr  = part + 256;                          // E+N

  int NB = (N + 255) / 256;
  int ET = E + N;

  // CSR build
  hipLaunchKernelGGL(k_init, dim3((N+255)/256), dim3(256), 0, stream, N, cnt);
  hipLaunchKernelGGL(k_count, dim3((E+255)/256), dim3(256), 0, stream, dsts, E, cnt);
  hipLaunchKernelGGL(k_scan_partial, dim3(NB), dim3(256), 0, stream, cnt, part, N);
  hipLaunchKernelGGL(k_scan_ex, dim3(1), dim3(256), 0, stream, part, NB);
  hipLaunchKernelGGL(k_scan_final, dim3(NB), dim3(256), 0, stream, cnt, part, offs, cnt, N);
  hipLaunchKernelGGL(k_scatter, dim3((ET+255)/256), dim3(256), 0, stream, srcs, dsts, E, N, cnt, csr);

  // casts / weight prep
  int n8 = N*256/8;
  hipLaunchKernelGGL(k_cast_x, dim3((n8+255)/256), dim3(256), 0, stream, x, xb, n8);
  hipLaunchKernelGGL(k_wt2, dim3((512*256+128*256+255)/256), dim3(256), 0, stream, W0, Wr0, W1, Wr1, WT0, WT1);

  int MB = (N + 127) / 128;
  int g0 = ((MB + 7) / 8) * 32;
  // layer0: buf0b[N][512] = xb @ [W0|Wr0]
  hipLaunchKernelGGL(k_mgemm, dim3(g0), dim3(256), 0, stream, xb, WT0, buf0b, 512, N, MB, 4);
  hipLaunchKernelGGL(k_al0, dim3((N*8+255)/256), dim3(256), 0, stream, buf0b, as0, ad0, als0, ald0, N);
  hipLaunchKernelGGL(k_gather0, dim3(N), dim3(256), 0, stream, buf0b, als0, ald0, offs, csr, b0, br0, h1b, N);

  // layer1: buf1b[N][128] = h1b @ [W1|Wr1]
  hipLaunchKernelGGL(k_mgemm, dim3(MB), dim3(256), 0, stream, h1b, WT1, buf1b, 128, N, MB, 1);
  hipLaunchKernelGGL(k_al1, dim3((N+3)/4), dim3(256), 0, stream, buf1b, as1, ad1, als1, ald1, N);
  hipLaunchKernelGGL(k_gather1, dim3(N), dim3(256), 0, stream, buf1b, als1, ald1, offs, csr, b1, br1, out, N);
}